// Round 2
// 325.024 us; speedup vs baseline: 1.6594x; 1.6594x over previous
//
#include <hip/hip_runtime.h>
#include <hip/hip_bf16.h>

typedef __bf16 bf16;
typedef __bf16 bf16x4 __attribute__((ext_vector_type(4)));
typedef __bf16 bf16x8 __attribute__((ext_vector_type(8)));
typedef float  f32x4  __attribute__((ext_vector_type(4)));

#define NN 4096
#define KK 16
#define CC 128
#define BN_TOT 16384

// ---------------------------------------------------------------------------
// K1/K5: Y = A(f32) @ W^T(f32) + b (fp32 out) + bn partials.  MFMA 16x16x32.
// 256 thr = 4 waves; 64 rows/block; each wave computes a 16x128 strip.
// Fragment layouts identical to (proven) k_attn:
//   A: lane l holds X[m = l&15][k = (l>>4)*8 + j] per 32-wide kc chunk
//   B: lane l holds W[n = jb*16 + (l&15)][k = (l>>4)*8 + j]
//   D: lane l reg g -> [row = (l>>4)*4+g][col = jb*16 + (l&15)]
// ---------------------------------------------------------------------------
__global__ __launch_bounds__(256) void k_lin(
    const float* __restrict__ A, const float* __restrict__ W,
    const float* __restrict__ bias, float* __restrict__ Y,
    float* __restrict__ partial) {
  __shared__ __attribute__((aligned(16))) bf16 WS[128][132];
  __shared__ float P1[128], P2[128];
  int tid = threadIdx.x, w = tid >> 6, l = tid & 63, quad = l >> 4, col = l & 15;
  int r0 = blockIdx.x * 64;
  int arow = r0 + w * 16 + col;

  if (tid < 128) { P1[tid] = 0.f; P2[tid] = 0.f; }

  // stage W (128x128 f32 -> bf16), 64 elems/thread
  for (int e = tid; e < 128 * 16; e += 256) {
    int r = e >> 4, c8 = e & 15;
    const float* p = W + r * CC + c8 * 8;
    f32x4 v0 = *(const f32x4*)p, v1 = *(const f32x4*)(p + 4);
    bf16x8 o;
    for (int i = 0; i < 4; i++) { o[i] = (bf16)v0[i]; o[i + 4] = (bf16)v1[i]; }
    *(bf16x8*)(&WS[r][c8 * 8]) = o;
  }

  // A-frags direct from global (each element read exactly once per block)
  bf16x8 a[4];
  for (int kc = 0; kc < 4; kc++) {
    int c0 = kc * 32 + quad * 8;
    f32x4 y0 = *(const f32x4*)(A + arow * CC + c0);
    f32x4 y1 = *(const f32x4*)(A + arow * CC + c0 + 4);
    bf16x8 o;
    for (int i = 0; i < 4; i++) { o[i] = (bf16)y0[i]; o[i + 4] = (bf16)y1[i]; }
    a[kc] = o;
  }

  f32x4 D[8];
  for (int jb = 0; jb < 8; jb++) {
    float bv = bias[jb * 16 + col];
    D[jb] = (f32x4){bv, bv, bv, bv};
  }
  __syncthreads();
  for (int jb = 0; jb < 8; jb++)
    for (int kc = 0; kc < 4; kc++) {
      bf16x8 bfrag = *(const bf16x8*)(&WS[jb * 16 + col][kc * 32 + quad * 8]);
      D[jb] = __builtin_amdgcn_mfma_f32_16x16x32_bf16(a[kc], bfrag, D[jb], 0, 0, 0);
    }

  // bn partials: per-column sums over this block's 64 rows.
  // Lane sums its 4 rows; shfl_xor(16/32) reduces across the 4 quads;
  // LDS atomics reduce across the 4 waves.
  for (int jb = 0; jb < 8; jb++) {
    float t1 = D[jb][0] + D[jb][1] + D[jb][2] + D[jb][3];
    float t2 = D[jb][0] * D[jb][0] + D[jb][1] * D[jb][1]
             + D[jb][2] * D[jb][2] + D[jb][3] * D[jb][3];
    t1 += __shfl_xor(t1, 16); t1 += __shfl_xor(t1, 32);
    t2 += __shfl_xor(t2, 16); t2 += __shfl_xor(t2, 32);
    if (quad == 0) {
      atomicAdd(&P1[jb * 16 + col], t1);
      atomicAdd(&P2[jb * 16 + col], t2);
    }
  }

  // fp32 store via per-wave LDS roundtrip (reuse WS region; B-frag reads done)
  __syncthreads();
  float (*Sf)[16][132] = (float (*)[16][132])WS;  // 4*16*132*4 = 33792 B == sizeof(WS)
  for (int jb = 0; jb < 8; jb++)
    for (int g = 0; g < 4; g++)
      Sf[w][quad * 4 + g][jb * 16 + col] = D[jb][g];
  int orow = r0 + w * 16 + (l >> 2), oc0 = (l & 3) * 32;
  for (int c4 = 0; c4 < 8; c4++) {
    f32x4 v = *(const f32x4*)(&Sf[w][l >> 2][oc0 + c4 * 4]);
    *(f32x4*)(Y + orow * CC + oc0 + c4 * 4) = v;
  }

  if (tid < 128) {
    partial[blockIdx.x * 256 + tid] = P1[tid];
    partial[blockIdx.x * 256 + 128 + tid] = P2[tid];
  }
}

// ---------------------------------------------------------------------------
__global__ __launch_bounds__(256) void k_finalize(
    const float* __restrict__ partial, const float* __restrict__ g,
    const float* __restrict__ b, float* __restrict__ stats, int NB) {
  __shared__ float sh[2][256];
  int t = threadIdx.x, c = t & 127, h = t >> 7;
  float s1 = 0.f, s2 = 0.f;
  for (int blk = h * (NB / 2); blk < (h + 1) * (NB / 2); blk++) {
    s1 += partial[blk * 256 + c];
    s2 += partial[blk * 256 + 128 + c];
  }
  sh[0][t] = s1; sh[1][t] = s2;
  __syncthreads();
  if (t < 128) {
    s1 = sh[0][t] + sh[0][t + 128];
    s2 = sh[1][t] + sh[1][t + 128];
    float mean = s1 * (1.0f / BN_TOT);
    float var  = s2 * (1.0f / BN_TOT) - mean * mean;
    float r = rsqrtf(var + 1e-5f);
    float sc = g[t] * r;
    stats[t] = sc;
    stats[128 + t] = b[t] - mean * sc;
  }
}

// ---------------------------------------------------------------------------
// K3: x = relu(bn2(y2)); q/k/v = x @ W^T (bf16 out).  MFMA 16x16x32.
// Same geometry as k_lin; bn+relu fused into the A-frag load; 3 weight
// matrices staged one at a time.
// ---------------------------------------------------------------------------
__global__ __launch_bounds__(256) void k_qkv(
    const float* __restrict__ Y, const float* __restrict__ stats,
    const float* __restrict__ Wq, const float* __restrict__ Wk, const float* __restrict__ Wv,
    bf16* __restrict__ Qo, bf16* __restrict__ Ko, bf16* __restrict__ Vo) {
  __shared__ __attribute__((aligned(16))) bf16 WS[128][132];
  __shared__ __attribute__((aligned(16))) bf16 S[4][16][132];
  int tid = threadIdx.x, w = tid >> 6, l = tid & 63, quad = l >> 4, col = l & 15;
  int r0 = blockIdx.x * 64;
  int arow = r0 + w * 16 + col;

  // A-frags: x = relu(bn(Y)) -> bf16, in fragment layout
  bf16x8 a[4];
  for (int kc = 0; kc < 4; kc++) {
    int c0 = kc * 32 + quad * 8;
    f32x4 y0  = *(const f32x4*)(Y + arow * CC + c0);
    f32x4 y1  = *(const f32x4*)(Y + arow * CC + c0 + 4);
    f32x4 sc0 = *(const f32x4*)(stats + c0);
    f32x4 sc1 = *(const f32x4*)(stats + c0 + 4);
    f32x4 sf0 = *(const f32x4*)(stats + 128 + c0);
    f32x4 sf1 = *(const f32x4*)(stats + 128 + c0 + 4);
    bf16x8 o;
    for (int i = 0; i < 4; i++) {
      o[i]     = (bf16)fmaxf(y0[i] * sc0[i] + sf0[i], 0.f);
      o[i + 4] = (bf16)fmaxf(y1[i] * sc1[i] + sf1[i], 0.f);
    }
    a[kc] = o;
  }

  const float* Ws[3] = {Wq, Wk, Wv};
  bf16* Os[3] = {Qo, Ko, Vo};
  for (int m = 0; m < 3; m++) {
    __syncthreads();  // protect WS from previous iteration's reads
    for (int e = tid; e < 128 * 16; e += 256) {
      int r = e >> 4, c8 = e & 15;
      const float* p = Ws[m] + r * CC + c8 * 8;
      f32x4 v0 = *(const f32x4*)p, v1 = *(const f32x4*)(p + 4);
      bf16x8 o;
      for (int i = 0; i < 4; i++) { o[i] = (bf16)v0[i]; o[i + 4] = (bf16)v1[i]; }
      *(bf16x8*)(&WS[r][c8 * 8]) = o;
    }
    __syncthreads();
    f32x4 D[8];
    for (int jb = 0; jb < 8; jb++) D[jb] = (f32x4){0.f, 0.f, 0.f, 0.f};
    for (int jb = 0; jb < 8; jb++)
      for (int kc = 0; kc < 4; kc++) {
        bf16x8 bfrag = *(const bf16x8*)(&WS[jb * 16 + col][kc * 32 + quad * 8]);
        D[jb] = __builtin_amdgcn_mfma_f32_16x16x32_bf16(a[kc], bfrag, D[jb], 0, 0, 0);
      }
    // bf16 out via per-wave LDS roundtrip -> 16B vectorized global stores
    for (int jb = 0; jb < 8; jb++)
      for (int g = 0; g < 4; g++)
        S[w][quad * 4 + g][jb * 16 + col] = (bf16)D[jb][g];
    int orow = r0 + w * 16 + (l >> 2), oc0 = (l & 3) * 32;
    for (int c8 = 0; c8 < 4; c8++) {
      bf16x8 v = *(const bf16x8*)(&S[w][l >> 2][oc0 + c8 * 8]);
      *(bf16x8*)(Os[m] + orow * CC + oc0 + c8 * 8) = v;
    }
  }
}

// ---------------------------------------------------------------------------
// K4: MFMA attention core. 4 points/WG, one wave per point, 256 threads.
// A-frag layout: lane holds X[m=l&15][k=quad*8+j] per 32-wide kc chunk.
// D layout: lane l reg g holds D[row=quad*4+g][col=jb*16+(l&15)]  (m89).
// ---------------------------------------------------------------------------
__global__ __launch_bounds__(256) void k_attn(
    const bf16* __restrict__ Q, const bf16* __restrict__ Kf, const bf16* __restrict__ Vf,
    const int* __restrict__ knn, const float* __restrict__ pose,
    const float* __restrict__ d_w1, const float* __restrict__ d_b1,
    const float* __restrict__ d_w2, const float* __restrict__ d_b2,
    const float* __restrict__ g_w1, const float* __restrict__ g_b1,
    const float* __restrict__ g_w2, const float* __restrict__ g_b2,
    float* __restrict__ Rs) {
  __shared__ bf16  WS[64][132];     // weight half: rows n = half*64 + r
  __shared__ bf16  S[4][16][132];   // per-wave D->A roundtrip scratch
  __shared__ float PoseS[4][64];
  __shared__ int   IDX[4][16];

  int tid = threadIdx.x, w = tid >> 6, l = tid & 63, quad = l >> 4, col = l & 15;
  int gp = blockIdx.x * 4 + w;
  int b  = gp >> 12;

  if (l < 16) IDX[w][l] = knn[gp * KK + l];
  PoseS[w][l] = pose[gp * 64 + l];

  // vv in D layout (registers): vpos[jb][g] = V[knn[quad*4+g]][jb*16+col]
  float vpos[8][4];
  for (int g = 0; g < 4; g++) {
    int grow = (b << 12) + IDX[w][quad * 4 + g];
    const bf16* vr = Vf + grow * CC + col;
    for (int jb = 0; jb < 8; jb++) vpos[jb][g] = (float)vr[jb * 16];
  }

  // h1 = relu(pose @ d_w1^T + d_b1) directly in A layout: m = col (neighbor k)
  bf16x8 aA[4];
  {
    float p0 = PoseS[w][col * 4 + 0], p1 = PoseS[w][col * 4 + 1];
    float p2 = PoseS[w][col * 4 + 2], p3 = PoseS[w][col * 4 + 3];
    for (int kc = 0; kc < 4; kc++) {
      bf16x8 v;
      for (int j = 0; j < 8; j++) {
        int c = kc * 32 + quad * 8 + j;
        f32x4 wr = *(const f32x4*)(d_w1 + c * 4);
        v[j] = (bf16)fmaxf(p0 * wr[0] + p1 * wr[1] + p2 * wr[2] + p3 * wr[3] + d_b1[c], 0.f);
      }
      aA[kc] = v;
    }
  }

  auto stageW = [&](const float* __restrict__ Wg, int half) {
    for (int e = tid; e < 64 * 16; e += 256) {
      int r = e >> 4, c8 = e & 15;
      const float* p = Wg + (half * 64 + r) * CC + c8 * 8;
      f32x4 v0 = *(const f32x4*)p, v1 = *(const f32x4*)(p + 4);
      bf16x8 o;
      for (int i = 0; i < 4; i++) { o[i] = (bf16)v0[i]; o[i + 4] = (bf16)v1[i]; }
      *(bf16x8*)(&WS[r][c8 * 8]) = o;
    }
  };
  // D[jb] = bias + aA @ Wg^T  (two staged halves)
  auto mfmaStage = [&](bf16x8 a[4], const float* __restrict__ Wg,
                       const float* __restrict__ bias, f32x4 D[8]) {
    for (int jb = 0; jb < 8; jb++) {
      float bv = bias[jb * 16 + col];
      D[jb] = (f32x4){bv, bv, bv, bv};
    }
    for (int half = 0; half < 2; half++) {
      __syncthreads();
      stageW(Wg, half);
      __syncthreads();
      for (int jbh = 0; jbh < 4; jbh++) {
        int jb = half * 4 + jbh;
        for (int kc = 0; kc < 4; kc++) {
          bf16x8 bfrag = *(const bf16x8*)(&WS[jbh * 16 + col][kc * 32 + quad * 8]);
          D[jb] = __builtin_amdgcn_mfma_f32_16x16x32_bf16(a[kc], bfrag, D[jb], 0, 0, 0);
        }
      }
    }
  };

  f32x4 D[8];
  // pos = h1 @ d_w2^T + d_b2
  mfmaStage(aA, d_w2, d_b2, D);
  for (int jb = 0; jb < 8; jb++)
    for (int g = 0; g < 4; g++) {
      vpos[jb][g] += D[jb][g];                               // vv + pos
      S[w][quad * 4 + g][jb * 16 + col] = (bf16)D[jb][g];    // pos -> scratch
    }
  // h = q - kk + pos in A layout (m = col neighbor)
  {
    int grow = (b << 12) + IDX[w][col];
    for (int kc = 0; kc < 4; kc++) {
      int c0 = kc * 32 + quad * 8;
      bf16x8 kkv = *(const bf16x8*)(Kf + grow * CC + c0);
      bf16x8 qv  = *(const bf16x8*)(Q + gp * CC + c0);
      bf16x8 pv  = *(const bf16x8*)(&S[w][col][c0]);
      bf16x8 hv;
      for (int j = 0; j < 8; j++)
        hv[j] = (bf16)((float)qv[j] - (float)kkv[j] + (float)pv[j]);
      aA[kc] = hv;
    }
  }
  // t = relu(h @ g_w1^T + g_b1)
  mfmaStage(aA, g_w1, g_b1, D);
  for (int jb = 0; jb < 8; jb++)
    for (int g = 0; g < 4; g++)
      S[w][quad * 4 + g][jb * 16 + col] = (bf16)fmaxf(D[jb][g], 0.f);
  for (int kc = 0; kc < 4; kc++)
    aA[kc] = *(const bf16x8*)(&S[w][col][kc * 32 + quad * 8]);
  // logits = t @ g_w2^T + g_b2
  mfmaStage(aA, g_w2, g_b2, D);

  // softmax over k (4 regs x 4 quads) per channel; weighted vpos sum
  const float sm = 0.08838834764831845f;  // 1/sqrt(128)
  for (int jb = 0; jb < 8; jb++) {
    float z[4], m = -1e30f;
    for (int g = 0; g < 4; g++) { z[g] = D[jb][g] * sm; m = fmaxf(m, z[g]); }
    m = fmaxf(m, __shfl_xor(m, 16));
    m = fmaxf(m, __shfl_xor(m, 32));
    float s = 0.f, p = 0.f;
    for (int g = 0; g < 4; g++) {
      float e = __expf(z[g] - m);
      s += e; p += e * vpos[jb][g];
    }
    s += __shfl_xor(s, 16); s += __shfl_xor(s, 32);
    p += __shfl_xor(p, 16); p += __shfl_xor(p, 32);
    if (quad == 0) Rs[gp * CC + jb * 16 + col] = p / s;
  }
}

// ---------------------------------------------------------------------------
// K7: out = relu(bn1(y1)) + new_points   (fp32 out)
// ---------------------------------------------------------------------------
__global__ __launch_bounds__(256) void k_out(
    const float* __restrict__ Y, const float* __restrict__ stats,
    const float* __restrict__ NP, float* __restrict__ Out) {
  int i0 = (blockIdx.x * 256 + threadIdx.x) * 4;
  int c0 = i0 & 127;
  f32x4 y  = *(const f32x4*)(Y + i0);
  f32x4 sc = *(const f32x4*)(stats + c0);
  f32x4 sh = *(const f32x4*)(stats + 128 + c0);
  f32x4 np = *(const f32x4*)(NP + i0);
  f32x4 o;
  for (int i = 0; i < 4; i++)
    o[i] = fmaxf(y[i] * sc[i] + sh[i], 0.f) + np[i];
  *(f32x4*)(Out + i0) = o;
}

__global__ void k_code(float* out, float code) {
  if (threadIdx.x == 0) out[1000003] = code;
}

// ---------------------------------------------------------------------------
extern "C" void kernel_launch(void* const* d_in, const int* in_sizes, int n_in,
                              void* d_out, int out_size, void* d_ws, size_t ws_size,
                              hipStream_t stream) {
  static const int expect[22] = {
    1048576, 262144, 2097152, 16384, 16384, 16384,
    16384, 128, 16384, 128,
    512, 128, 16384, 128,
    16384, 128, 128, 128,
    16384, 128, 128, 128
  };
  if (n_in != 22) { k_code<<<1, 64, 0, stream>>>((float*)d_out, 4194304.f); return; }
  for (int i = 0; i < 22; i++)
    if (in_sizes[i] != expect[i]) {
      k_code<<<1, 64, 0, stream>>>((float*)d_out, 262144.f * (float)(i + 1));
      return;
    }

  const float* pose  = (const float*)d_in[0];
  const int*   knn   = (const int*)d_in[1];
  const float* np_   = (const float*)d_in[2];
  const float* wq    = (const float*)d_in[3];
  const float* wk    = (const float*)d_in[4];
  const float* wv    = (const float*)d_in[5];
  const float* g_w1  = (const float*)d_in[6];
  const float* g_b1  = (const float*)d_in[7];
  const float* g_w2  = (const float*)d_in[8];
  const float* g_b2  = (const float*)d_in[9];
  const float* d_w1  = (const float*)d_in[10];
  const float* d_b1  = (const float*)d_in[11];
  const float* d_w2  = (const float*)d_in[12];
  const float* d_b2  = (const float*)d_in[13];
  const float* c1_w  = (const float*)d_in[14];
  const float* c1_b  = (const float*)d_in[15];
  const float* bn1_g = (const float*)d_in[16];
  const float* bn1_b = (const float*)d_in[17];
  const float* c2_w  = (const float*)d_in[18];
  const float* c2_b  = (const float*)d_in[19];
  const float* bn2_g = (const float*)d_in[20];
  const float* bn2_b = (const float*)d_in[21];

  float* y2      = (float*)d_ws;            // 2,097,152 f32 (reused as y1)
  float* res     = y2 + 2097152;            // 2,097,152 f32
  bf16*  qf      = (bf16*)(res + 2097152);  // 3 x 2,097,152 bf16
  bf16*  kf      = qf + 2097152;
  bf16*  vf      = kf + 2097152;
  float* partial = (float*)(vf + 2097152);  // 256*256 f32
  float* stats2  = partial + 65536;
  float* stats1  = stats2 + 256;

  size_t NEED = (size_t)((char*)(stats1 + 256) - (char*)d_ws);
  if (ws_size < NEED) {
    k_code<<<1, 64, 0, stream>>>((float*)d_out, 2097152.f);
    return;
  }

  k_lin     <<<256, 256, 0, stream>>>(np_, c2_w, c2_b, y2, partial);
  k_finalize<<<1, 256, 0, stream>>>(partial, bn2_g, bn2_b, stats2, 256);
  k_qkv     <<<256, 256, 0, stream>>>(y2, stats2, wq, wk, wv, qf, kf, vf);
  k_attn    <<<4096, 256, 0, stream>>>(qf, kf, vf, knn, pose,
                                       d_w1, d_b1, d_w2, d_b2,
                                       g_w1, g_b1, g_w2, g_b2, res);
  k_lin     <<<256, 256, 0, stream>>>(res, c1_w, c1_b, y2, partial);
  k_finalize<<<1, 256, 0, stream>>>(partial, bn1_g, bn1_b, stats1, 256);
  k_out     <<<2048, 256, 0, stream>>>(y2, stats1, np_, (float*)d_out);
}

// Round 3
// 270.943 us; speedup vs baseline: 1.9906x; 1.1996x over previous
//
#include <hip/hip_runtime.h>
#include <hip/hip_bf16.h>

typedef __bf16 bf16;
typedef __bf16 bf16x4 __attribute__((ext_vector_type(4)));
typedef __bf16 bf16x8 __attribute__((ext_vector_type(8)));
typedef float  f32x4  __attribute__((ext_vector_type(4)));

#define NN 4096
#define KK 16
#define CC 128
#define BN_TOT 16384

// ---------------------------------------------------------------------------
// K1/K5: Y = A(f32) @ W^T(f32) + b (fp32 out) + bn partials.  MFMA 16x16x32.
// 256 thr = 4 waves; 64 rows/block.  Weights in fragment-linear LDS:
// B-frag for (jb,kc) at WF[((jb*4+kc)*64 + l)*8] -> contiguous 1024B wave read.
// ---------------------------------------------------------------------------
__global__ __launch_bounds__(256) void k_lin(
    const float* __restrict__ A, const float* __restrict__ W,
    const float* __restrict__ bias, float* __restrict__ Y,
    float* __restrict__ partial) {
  __shared__ __attribute__((aligned(16))) bf16 WF[32 * 64 * 8];   // 32768 B
  __shared__ __attribute__((aligned(16))) float SF[4][16][132];   // 33792 B
  __shared__ float P1[128], P2[128];
  int tid = threadIdx.x, w = tid >> 6, l = tid & 63, quad = l >> 4, col = l & 15;
  int r0 = blockIdx.x * 64;
  int arow = r0 + w * 16 + col;

  if (tid < 128) { P1[tid] = 0.f; P2[tid] = 0.f; }

  // stage W (128x128 f32 -> bf16) into fragment-linear order
  for (int e = tid; e < 128 * 16; e += 256) {
    int r = e >> 4, c8 = e & 15;
    const float* p = W + r * CC + c8 * 8;
    f32x4 v0 = *(const f32x4*)p, v1 = *(const f32x4*)(p + 4);
    bf16x8 o;
    for (int i = 0; i < 4; i++) { o[i] = (bf16)v0[i]; o[i + 4] = (bf16)v1[i]; }
    int chunk = (r >> 4) * 4 + (c8 >> 2);
    int lane  = (c8 & 3) * 16 + (r & 15);
    *(bf16x8*)(&WF[(chunk * 64 + lane) * 8]) = o;
  }

  // A-frags direct from global
  bf16x8 a[4];
  for (int kc = 0; kc < 4; kc++) {
    int c0 = kc * 32 + quad * 8;
    f32x4 y0 = *(const f32x4*)(A + arow * CC + c0);
    f32x4 y1 = *(const f32x4*)(A + arow * CC + c0 + 4);
    bf16x8 o;
    for (int i = 0; i < 4; i++) { o[i] = (bf16)y0[i]; o[i + 4] = (bf16)y1[i]; }
    a[kc] = o;
  }

  f32x4 D[8];
  for (int jb = 0; jb < 8; jb++) {
    float bv = bias[jb * 16 + col];
    D[jb] = (f32x4){bv, bv, bv, bv};
  }
  __syncthreads();
  for (int jb = 0; jb < 8; jb++)
    for (int kc = 0; kc < 4; kc++) {
      bf16x8 bfrag = *(const bf16x8*)(&WF[((jb * 4 + kc) * 64 + l) * 8]);
      D[jb] = __builtin_amdgcn_mfma_f32_16x16x32_bf16(a[kc], bfrag, D[jb], 0, 0, 0);
    }

  // bn partials
  for (int jb = 0; jb < 8; jb++) {
    float t1 = D[jb][0] + D[jb][1] + D[jb][2] + D[jb][3];
    float t2 = D[jb][0] * D[jb][0] + D[jb][1] * D[jb][1]
             + D[jb][2] * D[jb][2] + D[jb][3] * D[jb][3];
    t1 += __shfl_xor(t1, 16); t1 += __shfl_xor(t1, 32);
    t2 += __shfl_xor(t2, 16); t2 += __shfl_xor(t2, 32);
    if (quad == 0) {
      atomicAdd(&P1[jb * 16 + col], t1);
      atomicAdd(&P2[jb * 16 + col], t2);
    }
  }

  // fp32 store via per-wave f32 scratch (wave-local: no barrier needed)
  for (int jb = 0; jb < 8; jb++)
    for (int g = 0; g < 4; g++)
      SF[w][quad * 4 + g][jb * 16 + col] = D[jb][g];
  int orow = r0 + w * 16 + (l >> 2), oc0 = (l & 3) * 32;
  for (int c4 = 0; c4 < 8; c4++) {
    f32x4 v = *(const f32x4*)(&SF[w][l >> 2][oc0 + c4 * 4]);
    *(f32x4*)(Y + orow * CC + oc0 + c4 * 4) = v;
  }

  __syncthreads();  // all waves' atomics done
  if (tid < 128) {
    partial[blockIdx.x * 256 + tid] = P1[tid];
    partial[blockIdx.x * 256 + 128 + tid] = P2[tid];
  }
}

// ---------------------------------------------------------------------------
__global__ __launch_bounds__(256) void k_finalize(
    const float* __restrict__ partial, const float* __restrict__ g,
    const float* __restrict__ b, float* __restrict__ stats, int NB) {
  __shared__ float sh[2][256];
  int t = threadIdx.x, c = t & 127, h = t >> 7;
  float s1 = 0.f, s2 = 0.f;
  for (int blk = h * (NB / 2); blk < (h + 1) * (NB / 2); blk++) {
    s1 += partial[blk * 256 + c];
    s2 += partial[blk * 256 + 128 + c];
  }
  sh[0][t] = s1; sh[1][t] = s2;
  __syncthreads();
  if (t < 128) {
    s1 = sh[0][t] + sh[0][t + 128];
    s2 = sh[1][t] + sh[1][t + 128];
    float mean = s1 * (1.0f / BN_TOT);
    float var  = s2 * (1.0f / BN_TOT) - mean * mean;
    float r = rsqrtf(var + 1e-5f);
    float sc = g[t] * r;
    stats[t] = sc;
    stats[128 + t] = b[t] - mean * sc;
  }
}

// ---------------------------------------------------------------------------
// K3: x = relu(bn2(y2)); q/k/v = x @ W^T (bf16 out).  768 blocks: block
// bid>>8 picks the weight matrix -> 3 blocks/CU, one stage phase each.
// ---------------------------------------------------------------------------
__global__ __launch_bounds__(256) void k_qkv(
    const float* __restrict__ Y, const float* __restrict__ stats,
    const float* __restrict__ Wq, const float* __restrict__ Wk, const float* __restrict__ Wv,
    bf16* __restrict__ Qo, bf16* __restrict__ Ko, bf16* __restrict__ Vo) {
  __shared__ __attribute__((aligned(16))) bf16 WF[32 * 64 * 8];   // 32768 B
  __shared__ __attribute__((aligned(16))) bf16 S[4][16][132];     // 16896 B
  int tid = threadIdx.x, w = tid >> 6, l = tid & 63, quad = l >> 4, col = l & 15;
  int m = blockIdx.x >> 8, rb = blockIdx.x & 255;
  int r0 = rb * 64;
  int arow = r0 + w * 16 + col;
  const float* Wg = (m == 0) ? Wq : (m == 1) ? Wk : Wv;
  bf16* Os = (m == 0) ? Qo : (m == 1) ? Ko : Vo;

  for (int e = tid; e < 128 * 16; e += 256) {
    int r = e >> 4, c8 = e & 15;
    const float* p = Wg + r * CC + c8 * 8;
    f32x4 v0 = *(const f32x4*)p, v1 = *(const f32x4*)(p + 4);
    bf16x8 o;
    for (int i = 0; i < 4; i++) { o[i] = (bf16)v0[i]; o[i + 4] = (bf16)v1[i]; }
    int chunk = (r >> 4) * 4 + (c8 >> 2);
    int lane  = (c8 & 3) * 16 + (r & 15);
    *(bf16x8*)(&WF[(chunk * 64 + lane) * 8]) = o;
  }

  // A-frags: x = relu(bn(Y)) -> bf16, in fragment layout
  bf16x8 a[4];
  for (int kc = 0; kc < 4; kc++) {
    int c0 = kc * 32 + quad * 8;
    f32x4 y0  = *(const f32x4*)(Y + arow * CC + c0);
    f32x4 y1  = *(const f32x4*)(Y + arow * CC + c0 + 4);
    f32x4 sc0 = *(const f32x4*)(stats + c0);
    f32x4 sc1 = *(const f32x4*)(stats + c0 + 4);
    f32x4 sf0 = *(const f32x4*)(stats + 128 + c0);
    f32x4 sf1 = *(const f32x4*)(stats + 128 + c0 + 4);
    bf16x8 o;
    for (int i = 0; i < 4; i++) {
      o[i]     = (bf16)fmaxf(y0[i] * sc0[i] + sf0[i], 0.f);
      o[i + 4] = (bf16)fmaxf(y1[i] * sc1[i] + sf1[i], 0.f);
    }
    a[kc] = o;
  }

  __syncthreads();
  f32x4 D[8];
  for (int jb = 0; jb < 8; jb++) D[jb] = (f32x4){0.f, 0.f, 0.f, 0.f};
  for (int jb = 0; jb < 8; jb++)
    for (int kc = 0; kc < 4; kc++) {
      bf16x8 bfrag = *(const bf16x8*)(&WF[((jb * 4 + kc) * 64 + l) * 8]);
      D[jb] = __builtin_amdgcn_mfma_f32_16x16x32_bf16(a[kc], bfrag, D[jb], 0, 0, 0);
    }
  for (int jb = 0; jb < 8; jb++)
    for (int g = 0; g < 4; g++)
      S[w][quad * 4 + g][jb * 16 + col] = (bf16)D[jb][g];
  int orow = r0 + w * 16 + (l >> 2), oc0 = (l & 3) * 32;
  for (int c8 = 0; c8 < 4; c8++) {
    bf16x8 v = *(const bf16x8*)(&S[w][l >> 2][oc0 + c8 * 8]);
    *(bf16x8*)(Os + orow * CC + oc0 + c8 * 8) = v;
  }
}

// ---------------------------------------------------------------------------
// K4: MFMA attention core.  512 thr = 8 waves; 64 points/block (8 per wave);
// grid = 256 (1 block/CU).  All three weights staged ONCE per block into
// fragment-linear LDS; per-point loop has no barriers (S is per-wave).
// A-frag layout: lane holds X[m=l&15][k=quad*8+j] per 32-wide kc chunk.
// D layout: lane l reg g holds D[row=quad*4+g][col=jb*16+(l&15)]  (m89).
// ---------------------------------------------------------------------------
__global__ __launch_bounds__(512) void k_attn(
    const bf16* __restrict__ Q, const bf16* __restrict__ Kf, const bf16* __restrict__ Vf,
    const int* __restrict__ knn, const float* __restrict__ pose,
    const float* __restrict__ d_w1, const float* __restrict__ d_b1,
    const float* __restrict__ d_w2, const float* __restrict__ d_b2,
    const float* __restrict__ g_w1, const float* __restrict__ g_b1,
    const float* __restrict__ g_w2, const float* __restrict__ g_b2,
    float* __restrict__ Rs) {
  __shared__ __attribute__((aligned(16))) bf16 WF[96 * 64 * 8];   // 98304 B
  __shared__ __attribute__((aligned(16))) bf16 S[8][16][132];     // 33792 B
  __shared__ __attribute__((aligned(16))) f32x4 DW1v[128];        // 2048 B (swizzled)
  __shared__ float DB1[128];                                      // 512 B
  __shared__ float BSf[384];                                      // 1536 B (d_b2,g_b1,g_b2)

  int tid = threadIdx.x, w = tid >> 6, l = tid & 63, quad = l >> 4, col = l & 15;

  // stage the three 128x128 weights, fragment-linear
  const float* Wg3[3] = {d_w2, g_w1, g_w2};
  for (int m = 0; m < 3; m++) {
    const float* Wg = Wg3[m];
    for (int e = tid; e < 128 * 16; e += 512) {
      int r = e >> 4, c8 = e & 15;
      const float* p = Wg + r * CC + c8 * 8;
      f32x4 v0 = *(const f32x4*)p, v1 = *(const f32x4*)(p + 4);
      bf16x8 o;
      for (int i = 0; i < 4; i++) { o[i] = (bf16)v0[i]; o[i + 4] = (bf16)v1[i]; }
      int chunk = m * 32 + (r >> 4) * 4 + (c8 >> 2);
      int lane  = (c8 & 3) * 16 + (r & 15);
      *(bf16x8*)(&WF[(chunk * 64 + lane) * 8]) = o;
    }
  }
  // d_w1 rows (f32x4), XOR-swizzled so the 4 quads hit different bank groups
  if (tid < 128) {
    int sc = tid ^ ((tid >> 3) & 7);
    DW1v[sc] = *(const f32x4*)(d_w1 + tid * 4);
    DB1[tid] = d_b1[tid];
  }
  if (tid < 384) {
    const float* bp = (tid < 128) ? d_b2 : (tid < 256) ? g_b1 : g_b2;
    BSf[tid] = bp[tid & 127];
  }
  __syncthreads();

#pragma unroll 1
  for (int p = 0; p < 8; p++) {
    int gp = blockIdx.x * 64 + w * 8 + p;
    int b  = gp >> 12;
    int i16 = knn[gp * KK + col];             // this lane's (col) neighbor idx
    f32x4 ps = *(const f32x4*)(pose + gp * 64 + col * 4);

    // h1 = relu(pose @ d_w1^T + d_b1) in A layout (m = col neighbor)
    bf16x8 aA[4];
    for (int kc = 0; kc < 4; kc++) {
      bf16x8 v;
      for (int j = 0; j < 8; j++) {
        int c = kc * 32 + quad * 8 + j;
        f32x4 wr = DW1v[c ^ ((c >> 3) & 7)];
        v[j] = (bf16)fmaxf(ps[0] * wr[0] + ps[1] * wr[1] + ps[2] * wr[2] + ps[3] * wr[3]
                           + DB1[c], 0.f);
      }
      aA[kc] = v;
    }

    f32x4 D[8];
    // pos = h1 @ d_w2^T + d_b2
    for (int jb = 0; jb < 8; jb++) {
      float bv = BSf[jb * 16 + col];
      D[jb] = (f32x4){bv, bv, bv, bv};
    }
    for (int jb = 0; jb < 8; jb++)
      for (int kc = 0; kc < 4; kc++) {
        bf16x8 bfrag = *(const bf16x8*)(&WF[((jb * 4 + kc) * 64 + l) * 8]);
        D[jb] = __builtin_amdgcn_mfma_f32_16x16x32_bf16(aA[kc], bfrag, D[jb], 0, 0, 0);
      }

    // vpos = V[knn] + pos, in D layout
    int vidx[4];
    for (int g = 0; g < 4; g++) vidx[g] = __shfl(i16, quad * 4 + g);
    float vpos[8][4];
    for (int g = 0; g < 4; g++) {
      const bf16* vr = Vf + ((b << 12) + vidx[g]) * CC + col;
      for (int jb = 0; jb < 8; jb++) vpos[jb][g] = (float)vr[jb * 16] + D[jb][g];
    }

    // pos -> per-wave scratch; h = q - kk + pos in A layout
    for (int jb = 0; jb < 8; jb++)
      for (int g = 0; g < 4; g++)
        S[w][quad * 4 + g][jb * 16 + col] = (bf16)D[jb][g];
    {
      int grow = (b << 12) + i16;
      for (int kc = 0; kc < 4; kc++) {
        int c0 = kc * 32 + quad * 8;
        bf16x8 kkv = *(const bf16x8*)(Kf + grow * CC + c0);
        bf16x8 qv  = *(const bf16x8*)(Q + gp * CC + c0);
        bf16x8 pv  = *(const bf16x8*)(&S[w][col][c0]);
        bf16x8 hv;
        for (int j = 0; j < 8; j++)
          hv[j] = (bf16)((float)qv[j] - (float)kkv[j] + (float)pv[j]);
        aA[kc] = hv;
      }
    }

    // t = relu(h @ g_w1^T + g_b1)
    for (int jb = 0; jb < 8; jb++) {
      float bv = BSf[128 + jb * 16 + col];
      D[jb] = (f32x4){bv, bv, bv, bv};
    }
    for (int jb = 0; jb < 8; jb++)
      for (int kc = 0; kc < 4; kc++) {
        bf16x8 bfrag = *(const bf16x8*)(&WF[((32 + jb * 4 + kc) * 64 + l) * 8]);
        D[jb] = __builtin_amdgcn_mfma_f32_16x16x32_bf16(aA[kc], bfrag, D[jb], 0, 0, 0);
      }
    for (int jb = 0; jb < 8; jb++)
      for (int g = 0; g < 4; g++)
        S[w][quad * 4 + g][jb * 16 + col] = (bf16)fmaxf(D[jb][g], 0.f);
    for (int kc = 0; kc < 4; kc++)
      aA[kc] = *(const bf16x8*)(&S[w][col][kc * 32 + quad * 8]);

    // logits = t @ g_w2^T + g_b2
    for (int jb = 0; jb < 8; jb++) {
      float bv = BSf[256 + jb * 16 + col];
      D[jb] = (f32x4){bv, bv, bv, bv};
    }
    for (int jb = 0; jb < 8; jb++)
      for (int kc = 0; kc < 4; kc++) {
        bf16x8 bfrag = *(const bf16x8*)(&WF[((64 + jb * 4 + kc) * 64 + l) * 8]);
        D[jb] = __builtin_amdgcn_mfma_f32_16x16x32_bf16(aA[kc], bfrag, D[jb], 0, 0, 0);
      }

    // softmax over k (4 regs x 4 quads) per channel; weighted vpos sum
    const float sm = 0.08838834764831845f;  // 1/sqrt(128)
    for (int jb = 0; jb < 8; jb++) {
      float z[4], m2 = -1e30f;
      for (int g = 0; g < 4; g++) { z[g] = D[jb][g] * sm; m2 = fmaxf(m2, z[g]); }
      m2 = fmaxf(m2, __shfl_xor(m2, 16));
      m2 = fmaxf(m2, __shfl_xor(m2, 32));
      float s = 0.f, pa = 0.f;
      for (int g = 0; g < 4; g++) {
        float e = __expf(z[g] - m2);
        s += e; pa += e * vpos[jb][g];
      }
      s  += __shfl_xor(s, 16);  s += __shfl_xor(s, 32);
      pa += __shfl_xor(pa, 16); pa += __shfl_xor(pa, 32);
      if (quad == 0) Rs[gp * CC + jb * 16 + col] = pa / s;
    }
  }
}

// ---------------------------------------------------------------------------
// K7: out = relu(bn1(y1)) + new_points   (fp32 out)
// ---------------------------------------------------------------------------
__global__ __launch_bounds__(256) void k_out(
    const float* __restrict__ Y, const float* __restrict__ stats,
    const float* __restrict__ NP, float* __restrict__ Out) {
  int i0 = (blockIdx.x * 256 + threadIdx.x) * 4;
  int c0 = i0 & 127;
  f32x4 y  = *(const f32x4*)(Y + i0);
  f32x4 sc = *(const f32x4*)(stats + c0);
  f32x4 sh = *(const f32x4*)(stats + 128 + c0);
  f32x4 np = *(const f32x4*)(NP + i0);
  f32x4 o;
  for (int i = 0; i < 4; i++)
    o[i] = fmaxf(y[i] * sc[i] + sh[i], 0.f) + np[i];
  *(f32x4*)(Out + i0) = o;
}

__global__ void k_code(float* out, float code) {
  if (threadIdx.x == 0) out[1000003] = code;
}

// ---------------------------------------------------------------------------
extern "C" void kernel_launch(void* const* d_in, const int* in_sizes, int n_in,
                              void* d_out, int out_size, void* d_ws, size_t ws_size,
                              hipStream_t stream) {
  static const int expect[22] = {
    1048576, 262144, 2097152, 16384, 16384, 16384,
    16384, 128, 16384, 128,
    512, 128, 16384, 128,
    16384, 128, 128, 128,
    16384, 128, 128, 128
  };
  if (n_in != 22) { k_code<<<1, 64, 0, stream>>>((float*)d_out, 4194304.f); return; }
  for (int i = 0; i < 22; i++)
    if (in_sizes[i] != expect[i]) {
      k_code<<<1, 64, 0, stream>>>((float*)d_out, 262144.f * (float)(i + 1));
      return;
    }

  const float* pose  = (const float*)d_in[0];
  const int*   knn   = (const int*)d_in[1];
  const float* np_   = (const float*)d_in[2];
  const float* wq    = (const float*)d_in[3];
  const float* wk    = (const float*)d_in[4];
  const float* wv    = (const float*)d_in[5];
  const float* g_w1  = (const float*)d_in[6];
  const float* g_b1  = (const float*)d_in[7];
  const float* g_w2  = (const float*)d_in[8];
  const float* g_b2  = (const float*)d_in[9];
  const float* d_w1  = (const float*)d_in[10];
  const float* d_b1  = (const float*)d_in[11];
  const float* d_w2  = (const float*)d_in[12];
  const float* d_b2  = (const float*)d_in[13];
  const float* c1_w  = (const float*)d_in[14];
  const float* c1_b  = (const float*)d_in[15];
  const float* bn1_g = (const float*)d_in[16];
  const float* bn1_b = (const float*)d_in[17];
  const float* c2_w  = (const float*)d_in[18];
  const float* c2_b  = (const float*)d_in[19];
  const float* bn2_g = (const float*)d_in[20];
  const float* bn2_b = (const float*)d_in[21];

  float* y2      = (float*)d_ws;            // 2,097,152 f32 (reused as y1)
  float* res     = y2 + 2097152;            // 2,097,152 f32
  bf16*  qf      = (bf16*)(res + 2097152);  // 3 x 2,097,152 bf16
  bf16*  kf      = qf + 2097152;
  bf16*  vf      = kf + 2097152;
  float* partial = (float*)(vf + 2097152);  // 256*256 f32
  float* stats2  = partial + 65536;
  float* stats1  = stats2 + 256;

  size_t NEED = (size_t)((char*)(stats1 + 256) - (char*)d_ws);
  if (ws_size < NEED) {
    k_code<<<1, 64, 0, stream>>>((float*)d_out, 2097152.f);
    return;
  }

  k_lin     <<<256, 256, 0, stream>>>(np_, c2_w, c2_b, y2, partial);
  k_finalize<<<1, 256, 0, stream>>>(partial, bn2_g, bn2_b, stats2, 256);
  k_qkv     <<<768, 256, 0, stream>>>(y2, stats2, wq, wk, wv, qf, kf, vf);
  k_attn    <<<256, 512, 0, stream>>>(qf, kf, vf, knn, pose,
                                      d_w1, d_b1, d_w2, d_b2,
                                      g_w1, g_b1, g_w2, g_b2, res);
  k_lin     <<<256, 256, 0, stream>>>(res, c1_w, c1_b, y2, partial);
  k_finalize<<<1, 256, 0, stream>>>(partial, bn1_g, bn1_b, stats1, 256);
  k_out     <<<2048, 256, 0, stream>>>(y2, stats1, np_, (float*)d_out);
}